// Round 1
// baseline (99.094 us; speedup 1.0000x reference)
//
#include <hip/hip_runtime.h>
#include <math.h>

#define B_ROWS 131072
#define NBLK (B_ROWS / 256)

__global__ __launch_bounds__(256) void qpinn_kernel(
    const float* __restrict__ xt,
    const float* __restrict__ W1, const float* __restrict__ b1,
    const float* __restrict__ W2, const float* __restrict__ b2,
    const float* __restrict__ Wr, const float* __restrict__ br,
    const float* __restrict__ Wi, const float* __restrict__ bi,
    const float* __restrict__ W3, const float* __restrict__ b3,
    const float* __restrict__ W4, const float* __restrict__ b4,
    float* __restrict__ out)
{
    __shared__ float sW1[32], sb1[16], sW2[64], sb2[4];
    __shared__ float sWr[80], sbr[20], sWi[80], sbi[20];
    __shared__ float sW3[320], sb3[16], sW4[32], sb4[2];
    __shared__ float swsum[4];

    const int t = threadIdx.x;

    // ---- cooperative weight staging (once per block) ----
    if (t < 32) sW1[t] = W1[t];
    if (t < 16) sb1[t] = b1[t];
    if (t < 64) sW2[t] = W2[t];
    if (t < 4)  sb2[t] = b2[t];
    // z_re = [z,z]  =>  fold Wr/Wi: eff[j][k] = W[j][k] + W[j+4][k], j<4
    if (t < 80) { sWr[t] = Wr[t] + Wr[80 + t]; sWi[t] = Wi[t] + Wi[80 + t]; }
    if (t < 20) { sbr[t] = br[t]; sbi[t] = bi[t]; }
    for (int i = t; i < 320; i += 256) sW3[i] = W3[i];
    if (t < 16) sb3[t] = b3[t];
    if (t < 32) sW4[t] = W4[t];
    if (t < 2)  sb4[t] = b4[t];
    __syncthreads();

    const int row = blockIdx.x * 256 + t;

    // ---- layer 1: h = tanh(xt @ W1 + b1) ----
    const float2 xv = ((const float2*)xt)[row];
    const float x0 = xv.x, x1 = xv.y;
    float h[16];
    #pragma unroll
    for (int o = 0; o < 16; ++o)
        h[o] = tanhf(fmaf(x0, sW1[o], fmaf(x1, sW1[16 + o], sb1[o])));

    // ---- layer 2: z = h @ W2 + b2 ----
    float z[4];
    #pragma unroll
    for (int o = 0; o < 4; ++o) {
        float acc = sb2[o];
        #pragma unroll
        for (int i = 0; i < 16; ++i) acc = fmaf(h[i], sW2[i * 4 + o], acc);
        z[o] = acc;
    }

    // ---- amplitudes: amp = z @ WrEff + br + i (z @ WiEff + bi) ----
    float ar[20], ai[20], p[20];
    float nrm2 = 0.0f;
    #pragma unroll
    for (int k = 0; k < 20; ++k) {
        float re = sbr[k], im = sbi[k];
        #pragma unroll
        for (int j = 0; j < 4; ++j) {
            re = fmaf(z[j], sWr[j * 20 + k], re);
            im = fmaf(z[j], sWi[j * 20 + k], im);
        }
        ar[k] = re; ai[k] = im;
        nrm2 = fmaf(re, re, fmaf(im, im, nrm2));
    }
    const float invn2 = 1.0f / nrm2;
    #pragma unroll
    for (int k = 0; k < 20; ++k)
        p[k] = (ar[k] * ar[k] + ai[k] * ai[k]) * invn2;

    // ---- entanglement entropy via block-diagonal rho_A ----
    // block sumA=0 (1x1): states 0,1,2,3
    const float l0 = p[0] + p[1] + p[2] + p[3];
    // block sumA=3 (rank-1): states 9,15,18,19
    const float l3 = p[9] + p[15] + p[18] + p[19];
    // block sumA=1: 2x3 rows (4,5,6) / (10,11,12) -> 2x2 Gram M M^H
    const float g00 = p[4] + p[5] + p[6];
    const float g11 = p[10] + p[11] + p[12];
    float cre = ar[4]*ar[10] + ai[4]*ai[10] + ar[5]*ar[11] + ai[5]*ai[11]
              + ar[6]*ar[12] + ai[6]*ai[12];
    float cim = ai[4]*ar[10] - ar[4]*ai[10] + ai[5]*ar[11] - ar[5]*ai[11]
              + ai[6]*ar[12] - ar[6]*ai[12];
    const float q2a = (cre * cre + cim * cim) * invn2 * invn2;
    const float da = g00 - g11;
    const float sa = sqrtf(fmaf(da, da, 4.0f * q2a));
    const float l1a = 0.5f * ((g00 + g11) + sa);
    const float l1b = 0.5f * ((g00 + g11) - sa);
    // block sumA=2: 3x2 cols (7,13,16) / (8,14,17) -> 2x2 Gram M^H M
    const float h00 = p[7] + p[13] + p[16];
    const float h11 = p[8] + p[14] + p[17];
    float dre = ar[7]*ar[8] + ai[7]*ai[8] + ar[13]*ar[14] + ai[13]*ai[14]
              + ar[16]*ar[17] + ai[16]*ai[17];
    float dim = ar[7]*ai[8] - ai[7]*ar[8] + ar[13]*ai[14] - ai[13]*ar[14]
              + ar[16]*ai[17] - ai[16]*ar[17];
    const float q2b = (dre * dre + dim * dim) * invn2 * invn2;
    const float db = h00 - h11;
    const float sb = sqrtf(fmaf(db, db, 4.0f * q2b));
    const float l2a = 0.5f * ((h00 + h11) + sb);
    const float l2b = 0.5f * ((h00 + h11) - sb);

    auto wlogw = [](float w) {
        w = fminf(fmaxf(w, 1e-12f), 1.0f);
        return w * logf(w);
    };
    // 4 exact-zero eigenvalues clip to 1e-12: +4*1e-12*ln(1e12) = 1.105e-10
    float ent = -(wlogw(l0) + wlogw(l1a) + wlogw(l1b)
                + wlogw(l2a) + wlogw(l2b) + wlogw(l3)) + 1.10524e-10f;

    // ---- head: out = tanh(p @ W3 + b3) @ W4 + b4 ----
    float tt[16];
    #pragma unroll
    for (int o = 0; o < 16; ++o) {
        float acc = sb3[o];
        #pragma unroll
        for (int k = 0; k < 20; ++k) acc = fmaf(p[k], sW3[k * 16 + o], acc);
        tt[o] = tanhf(acc);
    }
    float o0 = sb4[0], o1 = sb4[1];
    #pragma unroll
    for (int i = 0; i < 16; ++i) {
        o0 = fmaf(tt[i], sW4[2 * i], o0);
        o1 = fmaf(tt[i], sW4[2 * i + 1], o1);
    }

    out[row] = x0 * (1.0f - x0) * o0;   // u = x*(1-x)*q_u
    out[B_ROWS + row] = o1;             // ux_hat

    // ---- mean entropy reduction: wave shuffle -> LDS -> 1 atomic/block ----
    float v = ent;
    #pragma unroll
    for (int off = 32; off > 0; off >>= 1) v += __shfl_down(v, off, 64);
    if ((t & 63) == 0) swsum[t >> 6] = v;
    __syncthreads();
    if (t == 0) {
        const float bsum = swsum[0] + swsum[1] + swsum[2] + swsum[3];
        atomicAdd(&out[2 * B_ROWS], bsum * (1.0f / (float)B_ROWS));
    }
}

extern "C" void kernel_launch(void* const* d_in, const int* in_sizes, int n_in,
                              void* d_out, int out_size, void* d_ws, size_t ws_size,
                              hipStream_t stream) {
    float* out = (float*)d_out;
    // scalar accumulator must start at 0 (d_out is poisoned 0xAA before launch)
    hipMemsetAsync(out + 2 * B_ROWS, 0, sizeof(float), stream);
    qpinn_kernel<<<NBLK, 256, 0, stream>>>(
        (const float*)d_in[0],  // xt
        (const float*)d_in[1],  (const float*)d_in[2],   // W1, b1
        (const float*)d_in[3],  (const float*)d_in[4],   // W2, b2
        (const float*)d_in[5],  (const float*)d_in[6],   // Wr, br
        (const float*)d_in[7],  (const float*)d_in[8],   // Wi, bi
        (const float*)d_in[9],  (const float*)d_in[10],  // W3, b3
        (const float*)d_in[11], (const float*)d_in[12],  // W4, b4
        out);
}

// Round 2
// 95.557 us; speedup vs baseline: 1.0370x; 1.0370x over previous
//
#include <hip/hip_runtime.h>
#include <math.h>

#define B_ROWS 131072
#define NBLK (B_ROWS / 256)

// hardware-native helpers (err ~2^-21 rel; output threshold is 2.9e-2 -> huge headroom)
__device__ __forceinline__ float frcp(float x)  { return __builtin_amdgcn_rcpf(x); }
__device__ __forceinline__ float fsqrt(float x) { return __builtin_amdgcn_sqrtf(x); }
__device__ __forceinline__ float ftanh(float x) {
    // tanh(x) = (e^{2x}-1)/(e^{2x}+1); e^{2x} = 2^{x*2*log2(e)}
    float t = exp2f(x * 2.88539008f);
    return (t - 1.0f) * frcp(t + 1.0f);
}
__device__ __forceinline__ float fwlogw(float w) {
    // w*ln(w), clamped to [1e-12, 1]
    w = fminf(fmaxf(w, 1e-12f), 1.0f);
    return w * (__log2f(w) * 0.69314718f);
}

__global__ __launch_bounds__(256) void qpinn_kernel(
    const float* __restrict__ xt,
    const float* __restrict__ W1, const float* __restrict__ b1,
    const float* __restrict__ W2, const float* __restrict__ b2,
    const float* __restrict__ Wr, const float* __restrict__ br,
    const float* __restrict__ Wi, const float* __restrict__ bi,
    const float* __restrict__ W3, const float* __restrict__ b3,
    const float* __restrict__ W4, const float* __restrict__ b4,
    float* __restrict__ out)
{
    __shared__ float sW1[32], sb1[16], sW2[64], sb2[4];
    __shared__ float sWr[80], sbr[20], sWi[80], sbi[20];
    __shared__ float sW3[320], sb3[16], sW4[32], sb4[2];
    __shared__ float swsum[4];

    const int t = threadIdx.x;

    // ---- cooperative weight staging (once per block) ----
    if (t < 32) sW1[t] = W1[t];
    if (t < 16) sb1[t] = b1[t];
    if (t < 64) sW2[t] = W2[t];
    if (t < 4)  sb2[t] = b2[t];
    // z_re = [z,z]  =>  fold Wr/Wi: eff[j][k] = W[j][k] + W[j+4][k], j<4
    if (t < 80) { sWr[t] = Wr[t] + Wr[80 + t]; sWi[t] = Wi[t] + Wi[80 + t]; }
    if (t < 20) { sbr[t] = br[t]; sbi[t] = bi[t]; }
    for (int i = t; i < 320; i += 256) sW3[i] = W3[i];
    if (t < 16) sb3[t] = b3[t];
    if (t < 32) sW4[t] = W4[t];
    if (t < 2)  sb4[t] = b4[t];
    __syncthreads();

    const int row = blockIdx.x * 256 + t;

    // ---- layer 1: h = tanh(xt @ W1 + b1) ----
    const float2 xv = ((const float2*)xt)[row];
    const float x0 = xv.x, x1 = xv.y;
    float h[16];
    #pragma unroll
    for (int o = 0; o < 16; ++o)
        h[o] = ftanh(fmaf(x0, sW1[o], fmaf(x1, sW1[16 + o], sb1[o])));

    // ---- layer 2: z = h @ W2 + b2 ----
    float z[4];
    #pragma unroll
    for (int o = 0; o < 4; ++o) {
        float acc = sb2[o];
        #pragma unroll
        for (int i = 0; i < 16; ++i) acc = fmaf(h[i], sW2[i * 4 + o], acc);
        z[o] = acc;
    }

    // ---- amplitudes: amp = z @ WrEff + br + i (z @ WiEff + bi) ----
    float ar[20], ai[20], p[20];
    float nrm2 = 0.0f;
    #pragma unroll
    for (int k = 0; k < 20; ++k) {
        float re = sbr[k], im = sbi[k];
        #pragma unroll
        for (int j = 0; j < 4; ++j) {
            re = fmaf(z[j], sWr[j * 20 + k], re);
            im = fmaf(z[j], sWi[j * 20 + k], im);
        }
        ar[k] = re; ai[k] = im;
        nrm2 = fmaf(re, re, fmaf(im, im, nrm2));
    }
    const float invn2 = frcp(nrm2);
    #pragma unroll
    for (int k = 0; k < 20; ++k)
        p[k] = (ar[k] * ar[k] + ai[k] * ai[k]) * invn2;

    // ---- entanglement entropy via block-diagonal rho_A ----
    // fock basis split A=modes[0:2], B=modes[2:4]: rho_A block-diag by A-photon count
    // block sumA=0 (rank-1): states 0,1,2,3
    const float l0 = p[0] + p[1] + p[2] + p[3];
    // block sumA=3 (rank-1): states 9,15,18,19
    const float l3 = p[9] + p[15] + p[18] + p[19];
    // block sumA=1: 2x3 rows (4,5,6)/(10,11,12) -> eigvals of 2x2 Gram
    const float g00 = p[4] + p[5] + p[6];
    const float g11 = p[10] + p[11] + p[12];
    float cre = ar[4]*ar[10] + ai[4]*ai[10] + ar[5]*ar[11] + ai[5]*ai[11]
              + ar[6]*ar[12] + ai[6]*ai[12];
    float cim = ai[4]*ar[10] - ar[4]*ai[10] + ai[5]*ar[11] - ar[5]*ai[11]
              + ai[6]*ar[12] - ar[6]*ai[12];
    const float q2a = (cre * cre + cim * cim) * invn2 * invn2;
    const float da = g00 - g11;
    const float sa = fsqrt(fmaf(da, da, 4.0f * q2a));
    const float l1a = 0.5f * ((g00 + g11) + sa);
    const float l1b = 0.5f * ((g00 + g11) - sa);
    // block sumA=2: 3x2 cols (7,13,16)/(8,14,17) -> eigvals of 2x2 Gram
    const float h00 = p[7] + p[13] + p[16];
    const float h11 = p[8] + p[14] + p[17];
    float dre = ar[7]*ar[8] + ai[7]*ai[8] + ar[13]*ar[14] + ai[13]*ai[14]
              + ar[16]*ar[17] + ai[16]*ai[17];
    float dim = ar[7]*ai[8] - ai[7]*ar[8] + ar[13]*ai[14] - ai[13]*ar[14]
              + ar[16]*ai[17] - ai[16]*ar[17];
    const float q2b = (dre * dre + dim * dim) * invn2 * invn2;
    const float db = h00 - h11;
    const float sbv = fsqrt(fmaf(db, db, 4.0f * q2b));
    const float l2a = 0.5f * ((h00 + h11) + sbv);
    const float l2b = 0.5f * ((h00 + h11) - sbv);

    // 4 exact-zero eigenvalues clip to 1e-12: +4*1e-12*ln(1e12) = 1.105e-10
    float ent = -(fwlogw(l0) + fwlogw(l1a) + fwlogw(l1b)
                + fwlogw(l2a) + fwlogw(l2b) + fwlogw(l3)) + 1.10524e-10f;

    // ---- head: out = tanh(p @ W3 + b3) @ W4 + b4 ----
    float tt[16];
    #pragma unroll
    for (int o = 0; o < 16; ++o) {
        float acc = sb3[o];
        #pragma unroll
        for (int k = 0; k < 20; ++k) acc = fmaf(p[k], sW3[k * 16 + o], acc);
        tt[o] = ftanh(acc);
    }
    float o0 = sb4[0], o1 = sb4[1];
    #pragma unroll
    for (int i = 0; i < 16; ++i) {
        o0 = fmaf(tt[i], sW4[2 * i], o0);
        o1 = fmaf(tt[i], sW4[2 * i + 1], o1);
    }

    out[row] = x0 * (1.0f - x0) * o0;   // u = x*(1-x)*q_u
    out[B_ROWS + row] = o1;             // ux_hat

    // ---- mean entropy reduction: wave shuffle -> LDS -> 1 atomic/block ----
    float v = ent;
    #pragma unroll
    for (int off = 32; off > 0; off >>= 1) v += __shfl_down(v, off, 64);
    if ((t & 63) == 0) swsum[t >> 6] = v;
    __syncthreads();
    if (t == 0) {
        const float bsum = swsum[0] + swsum[1] + swsum[2] + swsum[3];
        atomicAdd(&out[2 * B_ROWS], bsum * (1.0f / (float)B_ROWS));
    }
}

extern "C" void kernel_launch(void* const* d_in, const int* in_sizes, int n_in,
                              void* d_out, int out_size, void* d_ws, size_t ws_size,
                              hipStream_t stream) {
    float* out = (float*)d_out;
    // scalar accumulator must start at 0 (d_out is poisoned 0xAA before launch)
    hipMemsetAsync(out + 2 * B_ROWS, 0, sizeof(float), stream);
    qpinn_kernel<<<NBLK, 256, 0, stream>>>(
        (const float*)d_in[0],  // xt
        (const float*)d_in[1],  (const float*)d_in[2],   // W1, b1
        (const float*)d_in[3],  (const float*)d_in[4],   // W2, b2
        (const float*)d_in[5],  (const float*)d_in[6],   // Wr, br
        (const float*)d_in[7],  (const float*)d_in[8],   // Wi, bi
        (const float*)d_in[9],  (const float*)d_in[10],  // W3, b3
        (const float*)d_in[11], (const float*)d_in[12],  // W4, b4
        out);
}